// Round 1
// baseline (868.561 us; speedup 1.0000x reference)
//
#include <hip/hip_runtime.h>

namespace {
constexpr int Bc = 4, Hc = 16, Sc = 1024, Dc = 64;
constexpr int BH = Bc * Hc;
constexpr int TQ = 64, TK = 64;
constexpr int NJ = 33;          // rel indices 0..32 (causal => k-q+32 in [0,32])
constexpr int STR = 68;         // LDS row stride (floats), 16B aligned, pad vs 64
constexpr float SCALE = 0.125f; // 1/sqrt(64)
constexpr float NEG = -1e30f;
}

// Compute 4x4 score partial dots: rows r_i = 16*i+rt, cols c_j = 16*j+tc.
__device__ __forceinline__ void compute_dots(const float* Qs, const float* Ks,
                                             int rt, int tc, float s[4][4]) {
    #pragma unroll
    for (int i = 0; i < 4; ++i)
        #pragma unroll
        for (int j = 0; j < 4; ++j) s[i][j] = 0.f;
    #pragma unroll 4
    for (int d4 = 0; d4 < 16; ++d4) {
        float4 qv[4], kv[4];
        #pragma unroll
        for (int i = 0; i < 4; ++i)
            qv[i] = *(const float4*)(Qs + (16 * i + rt) * STR + d4 * 4);
        #pragma unroll
        for (int j = 0; j < 4; ++j)
            kv[j] = *(const float4*)(Ks + (16 * j + tc) * STR + d4 * 4);
        #pragma unroll
        for (int i = 0; i < 4; ++i)
            #pragma unroll
            for (int j = 0; j < 4; ++j)
                s[i][j] += qv[i].x * kv[j].x + qv[i].y * kv[j].y +
                           qv[i].z * kv[j].z + qv[i].w * kv[j].w;
    }
}

__global__ __launch_bounds__(256, 2)
void relattn(const float* __restrict__ Qg, const float* __restrict__ Kg,
             const float* __restrict__ Vg, const float* __restrict__ pek,
             const float* __restrict__ pev, float* __restrict__ outg,
             float* __restrict__ pbuf)
{
    __shared__ float Qs[TQ * STR];
    __shared__ float KVs[TK * STR];   // K in score phases, V in PV phase
    __shared__ float Ps[TK * STR];    // p tile, transposed [c][r]
    __shared__ float Ts[TQ * NJ];     // rel score table t[r][j]
    __shared__ float Ws[TQ * NJ];     // rel output weights w[r][j]

    const int qt = blockIdx.x;   // 0..15
    const int bh = blockIdx.y;   // 0..63
    const int tid = threadIdx.x;
    const int rt = tid >> 4;     // 0..15
    const int tc = tid & 15;     // 0..15

    const float* Qbh = Qg + (size_t)bh * Sc * Dc;
    const float* Kbh = Kg + (size_t)bh * Sc * Dc;
    const float* Vbh = Vg + (size_t)bh * Sc * Dc;
    float* pbh = pbuf + (size_t)bh * Sc * Sc;
    float* obh = outg + (size_t)bh * Sc * Dc;

    // ---- load Q tile, zero Ws ----
    #pragma unroll
    for (int it = 0; it < 4; ++it) {
        int rr = rt + it * 16;
        *(float4*)(Qs + rr * STR + tc * 4) =
            *(const float4*)(Qbh + (size_t)(qt * TQ + rr) * Dc + tc * 4);
    }
    for (int idx = tid; idx < TQ * NJ; idx += 256) Ws[idx] = 0.f;
    __syncthreads();

    // ---- rel score table Ts[r][j] = Q[r] . pe_k[j] ----
    for (int idx = tid; idx < TQ * NJ; idx += 256) {
        int r = idx / NJ, j = idx - r * NJ;
        const float4* qr = (const float4*)(Qs + r * STR);
        const float4* pj = (const float4*)(pek + j * Dc);
        float acc = 0.f;
        #pragma unroll
        for (int d4 = 0; d4 < 16; ++d4) {
            float4 a = qr[d4], b = pj[d4];
            acc += a.x * b.x + a.y * b.y + a.z * b.z + a.w * b.w;
        }
        Ts[idx] = acc;
    }
    __syncthreads();

    const int q_[4] = { qt * TQ + rt, qt * TQ + 16 + rt,
                        qt * TQ + 32 + rt, qt * TQ + 48 + rt };

    // ---- pass 1: online softmax stats (m, l) per row ----
    float m_i[4], l_i[4];
    #pragma unroll
    for (int i = 0; i < 4; ++i) { m_i[i] = NEG; l_i[i] = 0.f; }

    for (int kt = 0; kt <= qt; ++kt) {
        #pragma unroll
        for (int it = 0; it < 4; ++it) {
            int rr = rt + it * 16;
            *(float4*)(KVs + rr * STR + tc * 4) =
                *(const float4*)(Kbh + (size_t)(kt * TK + rr) * Dc + tc * 4);
        }
        __syncthreads();

        float s[4][4];
        compute_dots(Qs, KVs, rt, tc, s);

        #pragma unroll
        for (int i = 0; i < 4; ++i) {
            const int q = q_[i];
            const int r = 16 * i + rt;
            float sv[4];
            float rmax = NEG;
            #pragma unroll
            for (int j = 0; j < 4; ++j) {
                int k = kt * TK + 16 * j + tc;
                int jrel = k - q + 32;
                int jcl = jrel < 0 ? 0 : (jrel > 32 ? 32 : jrel);
                float v = (jrel > 32) ? NEG : (s[i][j] + Ts[r * NJ + jcl]) * SCALE;
                sv[j] = v;
                rmax = fmaxf(rmax, v);
            }
            rmax = fmaxf(rmax, __shfl_xor(rmax, 1));
            rmax = fmaxf(rmax, __shfl_xor(rmax, 2));
            rmax = fmaxf(rmax, __shfl_xor(rmax, 4));
            rmax = fmaxf(rmax, __shfl_xor(rmax, 8));
            float mn = fmaxf(m_i[i], rmax);
            float psum = 0.f;
            #pragma unroll
            for (int j = 0; j < 4; ++j) psum += __expf(sv[j] - mn);
            psum += __shfl_xor(psum, 1);
            psum += __shfl_xor(psum, 2);
            psum += __shfl_xor(psum, 4);
            psum += __shfl_xor(psum, 8);
            l_i[i] = l_i[i] * __expf(m_i[i] - mn) + psum;
            m_i[i] = mn;
        }
        __syncthreads();
    }

    // ---- zero-fill fully-masked column range [ (qt+1)*64, S ) ----
    {
        const int zbase = (qt + 1) * TQ;
        if (zbase < Sc) {
            const int z4 = (Sc - zbase) >> 2;
            const float4 z = make_float4(0.f, 0.f, 0.f, 0.f);
            for (int r = 0; r < TQ; ++r) {
                float4* rowp = (float4*)(pbh + (size_t)(qt * TQ + r) * Sc + zbase);
                for (int c4 = tid; c4 < z4; c4 += 256) rowp[c4] = z;
            }
        }
    }

    float rinv[4];
    #pragma unroll
    for (int i = 0; i < 4; ++i) rinv[i] = 1.f / l_i[i];

    float4 oacc[4];
    #pragma unroll
    for (int i = 0; i < 4; ++i) oacc[i] = make_float4(0.f, 0.f, 0.f, 0.f);
    float wsum0[4] = {0.f, 0.f, 0.f, 0.f};

    // ---- pass 2: recompute scores -> p (write), PV accumulate ----
    for (int kt = 0; kt <= qt; ++kt) {
        #pragma unroll
        for (int it = 0; it < 4; ++it) {
            int rr = rt + it * 16;
            *(float4*)(KVs + rr * STR + tc * 4) =
                *(const float4*)(Kbh + (size_t)(kt * TK + rr) * Dc + tc * 4);
        }
        // prefetch V tile into registers (overlaps with score compute)
        float4 vreg[4];
        #pragma unroll
        for (int it = 0; it < 4; ++it)
            vreg[it] = *(const float4*)(Vbh + (size_t)(kt * TK + rt + it * 16) * Dc + tc * 4);
        __syncthreads();

        float s[4][4];
        compute_dots(Qs, KVs, rt, tc, s);

        #pragma unroll
        for (int i = 0; i < 4; ++i) {
            const int q = q_[i];
            const int r = 16 * i + rt;
            #pragma unroll
            for (int j = 0; j < 4; ++j) {
                int k = kt * TK + 16 * j + tc;
                int jrel = k - q + 32;
                int jcl = jrel < 0 ? 0 : (jrel > 32 ? 32 : jrel);
                float v = (jrel > 32) ? NEG : (s[i][j] + Ts[r * NJ + jcl]) * SCALE;
                float p = __expf(v - m_i[i]) * rinv[i];
                pbh[(size_t)q * Sc + k] = p;
                Ps[(16 * j + tc) * STR + r] = p;
                if (jrel <= 0)       wsum0[i] += p;
                else if (jrel <= 32) Ws[r * NJ + jrel] = p;
            }
        }
        __syncthreads();   // scores done reading KVs(K); Ps complete

        #pragma unroll
        for (int it = 0; it < 4; ++it)
            *(float4*)(KVs + (rt + it * 16) * STR + tc * 4) = vreg[it];
        __syncthreads();   // V tile staged

        #pragma unroll 8
        for (int c = 0; c < TK; ++c) {
            float4 vv = *(const float4*)(KVs + c * STR + tc * 4);
            #pragma unroll
            for (int i = 0; i < 4; ++i) {
                float p = Ps[c * STR + 16 * i + rt];
                oacc[i].x = fmaf(p, vv.x, oacc[i].x);
                oacc[i].y = fmaf(p, vv.y, oacc[i].y);
                oacc[i].z = fmaf(p, vv.z, oacc[i].z);
                oacc[i].w = fmaf(p, vv.w, oacc[i].w);
            }
        }
        __syncthreads();   // PV done reading KVs before next tile's K load
    }

    // ---- fold far-past mass into Ws[r][0] ----
    #pragma unroll
    for (int i = 0; i < 4; ++i) {
        float wv = wsum0[i];
        wv += __shfl_xor(wv, 1);
        wv += __shfl_xor(wv, 2);
        wv += __shfl_xor(wv, 4);
        wv += __shfl_xor(wv, 8);
        if (tc == 0) Ws[(16 * i + rt) * NJ + 0] = wv;
    }
    __syncthreads();

    // ---- epilogue: out += sum_j Ws[r][j] * pe_v[j] ; store ----
    #pragma unroll 4
    for (int jr = 0; jr < NJ; ++jr) {
        float4 pv = *(const float4*)(pev + jr * Dc + tc * 4);
        #pragma unroll
        for (int i = 0; i < 4; ++i) {
            float w = Ws[(16 * i + rt) * NJ + jr];
            oacc[i].x = fmaf(w, pv.x, oacc[i].x);
            oacc[i].y = fmaf(w, pv.y, oacc[i].y);
            oacc[i].z = fmaf(w, pv.z, oacc[i].z);
            oacc[i].w = fmaf(w, pv.w, oacc[i].w);
        }
    }
    #pragma unroll
    for (int i = 0; i < 4; ++i)
        *(float4*)(obh + (size_t)q_[i] * Dc + tc * 4) = oacc[i];
}

extern "C" void kernel_launch(void* const* d_in, const int* in_sizes, int n_in,
                              void* d_out, int out_size, void* d_ws, size_t ws_size,
                              hipStream_t stream)
{
    const float* Q   = (const float*)d_in[0];
    const float* K   = (const float*)d_in[1];
    const float* V   = (const float*)d_in[2];
    const float* pek = (const float*)d_in[3];
    const float* pev = (const float*)d_in[4];
    float* out  = (float*)d_out;
    float* pbuf = out + (size_t)BH * Sc * Dc;   // p_attn follows output

    dim3 grid(Sc / TQ, BH);
    relattn<<<grid, 256, 0, stream>>>(Q, K, V, pek, pev, out, pbuf);
}

// Round 2
// 391.458 us; speedup vs baseline: 2.2188x; 2.2188x over previous
//
#include <hip/hip_runtime.h>

typedef __attribute__((ext_vector_type(8))) short bfrag;
typedef __attribute__((ext_vector_type(4))) float ffrag;

namespace {
constexpr int Sc = 1024, Dc = 64;
constexpr int P2 = 72;          // bf16 LDS pitch (144 B) — all-distinct banks for frag reads
constexpr float SCALE = 0.125f; // 1/sqrt(64)
}

__device__ __forceinline__ unsigned short f2bf(float f) {
    unsigned u = __builtin_bit_cast(unsigned, f);
    u += 0x7fffu + ((u >> 16) & 1u);
    return (unsigned short)(u >> 16);
}
__device__ __forceinline__ bfrag pack8(float4 a, float4 b) {
    bfrag r;
    r[0] = (short)f2bf(a.x); r[1] = (short)f2bf(a.y);
    r[2] = (short)f2bf(a.z); r[3] = (short)f2bf(a.w);
    r[4] = (short)f2bf(b.x); r[5] = (short)f2bf(b.y);
    r[6] = (short)f2bf(b.z); r[7] = (short)f2bf(b.w);
    return r;
}
#define MFMA(a, b, c) __builtin_amdgcn_mfma_f32_16x16x32_bf16((a), (b), (c), 0, 0, 0)

__global__ __launch_bounds__(256, 3)
void relattn(const float* __restrict__ Qg, const float* __restrict__ Kg,
             const float* __restrict__ Vg, const float* __restrict__ pek,
             const float* __restrict__ pev, float* __restrict__ outg,
             float* __restrict__ pbuf)
{
    // LDS arena: Qs 9216 | Ks 9216 | Vt 9216 | Pt 9216 | Ts 8448 | Ws 8192 | W0 256 = 53760 B
    // Ot (64x68 f32 = 17408 B) aliases Ks+Vt (epilogue only).
    __shared__ __align__(16) char smem[53760];
    unsigned short* Qs = (unsigned short*)smem;
    unsigned short* Ks = (unsigned short*)(smem + 9216);
    unsigned short* Vt = (unsigned short*)(smem + 18432);
    unsigned short* Pt = (unsigned short*)(smem + 27648);
    float* Ts = (float*)(smem + 36864);   // [64][33]
    float* Ws = (float*)(smem + 45312);   // [64][32]  (col = jrel-1)
    float* W0 = (float*)(smem + 53504);   // [64]
    float* Ot = (float*)(smem + 9216);    // [64][68], aliases Ks+Vt

    const int tid  = threadIdx.x;
    const int bh   = blockIdx.y;
    const int wv   = tid >> 6;
    const int lane = tid & 63;
    const int n    = lane & 15;
    const int quad = lane >> 4;

    const float* Qbh = Qg + (size_t)bh * Sc * Dc;
    const float* Kbh = Kg + (size_t)bh * Sc * Dc;
    const float* Vbh = Vg + (size_t)bh * Sc * Dc;
    float* pbh = pbuf + (size_t)bh * Sc * Sc;
    float* obh = outg + (size_t)bh * Sc * Dc;

    const int sr  = tid >> 2;           // staging row 0..63
    const int sc  = (tid & 3) * 16;     // staging col (floats)
    const int kp  = tid & 31;           // V-transpose k-pair
    const int vd0 = (tid >> 5) * 8;     // V-transpose d base

    for (int half = 0; half < 2; ++half) {
        const int qt = half ? (15 - (int)blockIdx.x) : (int)blockIdx.x;
        const int qrow = wv * 16 + quad * 4;   // C-layout row base for this lane

        __syncthreads();   // previous half's epilogue fully done with LDS

        // ---- stage Q tile (fp32 -> bf16) ----
        {
            const float* src = Qbh + (size_t)(qt * 64 + sr) * Dc + sc;
            float4 a = *(const float4*)(src);
            float4 b = *(const float4*)(src + 4);
            float4 c = *(const float4*)(src + 8);
            float4 d = *(const float4*)(src + 12);
            *(bfrag*)&Qs[sr * P2 + sc]     = pack8(a, b);
            *(bfrag*)&Qs[sr * P2 + sc + 8] = pack8(c, d);
        }
        // ---- zero Ws ----
        for (int idx = tid; idx < 64 * 32; idx += 256) Ws[idx] = 0.f;
        // ---- stage pe_k (rows 0..32) into Ks; zero rows 33..47 ----
        for (int i = tid; i < 135; i += 256) {          // zero [33*72, 48*72)
            bfrag z = {};
            *(bfrag*)&Ks[33 * P2 + i * 8] = z;
        }
        if (tid < 132) {
            int r = tid >> 2, c0 = (tid & 3) * 16;
            const float* src = pek + (size_t)r * Dc + c0;
            float4 a = *(const float4*)(src);
            float4 b = *(const float4*)(src + 4);
            float4 c = *(const float4*)(src + 8);
            float4 d = *(const float4*)(src + 12);
            *(bfrag*)&Ks[r * P2 + c0]     = pack8(a, b);
            *(bfrag*)&Ks[r * P2 + c0 + 8] = pack8(c, d);
        }
        __syncthreads();

        // ---- hoist Q A-frags (row = wv*16+n, k = d) ----
        bfrag qa0 = *(bfrag*)&Qs[(wv * 16 + n) * P2 + quad * 8];
        bfrag qa1 = *(bfrag*)&Qs[(wv * 16 + n) * P2 + 32 + quad * 8];

        // ---- Ts = Q . pe_k^T via MFMA (j in 0..47, keep j<=32) ----
        #pragma unroll
        for (int sub = 0; sub < 3; ++sub) {
            bfrag b0 = *(bfrag*)&Ks[(sub * 16 + n) * P2 + quad * 8];
            bfrag b1 = *(bfrag*)&Ks[(sub * 16 + n) * P2 + 32 + quad * 8];
            ffrag c = {};
            c = MFMA(qa0, b0, c);
            c = MFMA(qa1, b1, c);
            int j = sub * 16 + n;
            if (j <= 32) {
                #pragma unroll
                for (int reg = 0; reg < 4; ++reg)
                    Ts[(qrow + reg) * 33 + j] = c[reg];
            }
        }
        __syncthreads();

        float ts0[4];
        #pragma unroll
        for (int reg = 0; reg < 4; ++reg) ts0[reg] = Ts[(qrow + reg) * 33];

        // ---- zero-fill fully-masked p region (cols >= (qt+1)*64) ----
        {
            const int zb = (qt + 1) * 64;
            if (zb < Sc) {
                const int z4 = (Sc - zb) >> 2;
                const float4 z = make_float4(0.f, 0.f, 0.f, 0.f);
                for (int r = 0; r < 64; ++r) {
                    float4* rp = (float4*)(pbh + (size_t)(qt * 64 + r) * Sc + zb);
                    for (int c4 = tid; c4 < z4; c4 += 256) rp[c4] = z;
                }
            }
        }

        // ================= pass 1: l = sum(exp(s)) =================
        float lsum[4] = {0.f, 0.f, 0.f, 0.f};
        for (int kt = 0; kt <= qt; ++kt) {
            const bool bnd = (kt >= qt - 1);
            const float* ksrc = Kbh + (size_t)(kt * 64 + sr) * Dc + sc;
            float4 ka = *(const float4*)(ksrc);
            float4 kb = *(const float4*)(ksrc + 4);
            float4 kc = *(const float4*)(ksrc + 8);
            float4 kd = *(const float4*)(ksrc + 12);
            __syncthreads();   // previous reads of Ks done
            *(bfrag*)&Ks[sr * P2 + sc]     = pack8(ka, kb);
            *(bfrag*)&Ks[sr * P2 + sc + 8] = pack8(kc, kd);
            __syncthreads();
            #pragma unroll
            for (int sub = 0; sub < 4; ++sub) {
                bfrag b0 = *(bfrag*)&Ks[(sub * 16 + n) * P2 + quad * 8];
                bfrag b1 = *(bfrag*)&Ks[(sub * 16 + n) * P2 + 32 + quad * 8];
                ffrag c = {};
                c = MFMA(qa0, b0, c);
                c = MFMA(qa1, b1, c);
                const int k = kt * 64 + sub * 16 + n;
                if (!bnd) {
                    #pragma unroll
                    for (int reg = 0; reg < 4; ++reg)
                        lsum[reg] += __expf((c[reg] + ts0[reg]) * SCALE);
                } else {
                    #pragma unroll
                    for (int reg = 0; reg < 4; ++reg) {
                        int jrel = k - (qt * 64 + qrow + reg) + 32;
                        if (jrel <= 32) {
                            int jcl = jrel < 0 ? 0 : jrel;
                            lsum[reg] += __expf((c[reg] + Ts[(qrow + reg) * 33 + jcl]) * SCALE);
                        }
                    }
                }
            }
        }
        float rinv[4];
        #pragma unroll
        for (int reg = 0; reg < 4; ++reg) {
            float l = lsum[reg];
            l += __shfl_xor(l, 1);
            l += __shfl_xor(l, 2);
            l += __shfl_xor(l, 4);
            l += __shfl_xor(l, 8);
            rinv[reg] = 1.f / l;
        }

        // ================= pass 2: p + O^T = V^T P^T =================
        ffrag oacc[4];
        #pragma unroll
        for (int i = 0; i < 4; ++i) { ffrag z = {}; oacc[i] = z; }

        for (int kt = 0; kt <= qt; ++kt) {
            const bool bnd = (kt >= qt - 1);
            const float* ksrc = Kbh + (size_t)(kt * 64 + sr) * Dc + sc;
            float4 ka = *(const float4*)(ksrc);
            float4 kb = *(const float4*)(ksrc + 4);
            float4 kc = *(const float4*)(ksrc + 8);
            float4 kd = *(const float4*)(ksrc + 12);
            const float* vsrc = Vbh + (size_t)(kt * 64 + 2 * kp) * Dc + vd0;
            float4 v0a = *(const float4*)(vsrc);
            float4 v0b = *(const float4*)(vsrc + 4);
            float4 v1a = *(const float4*)(vsrc + Dc);
            float4 v1b = *(const float4*)(vsrc + Dc + 4);
            __syncthreads();   // previous PV reads of Ks/Vt/Pt done
            *(bfrag*)&Ks[sr * P2 + sc]     = pack8(ka, kb);
            *(bfrag*)&Ks[sr * P2 + sc + 8] = pack8(kc, kd);
            {
                float r0[8] = {v0a.x, v0a.y, v0a.z, v0a.w, v0b.x, v0b.y, v0b.z, v0b.w};
                float r1[8] = {v1a.x, v1a.y, v1a.z, v1a.w, v1b.x, v1b.y, v1b.z, v1b.w};
                #pragma unroll
                for (int i = 0; i < 8; ++i) {
                    unsigned pk = (unsigned)f2bf(r0[i]) | ((unsigned)f2bf(r1[i]) << 16);
                    *(unsigned*)&Vt[(vd0 + i) * P2 + 2 * kp] = pk;   // Vt[d][k]
                }
            }
            __syncthreads();
            // scores -> p (global + Pt), rel-v weight capture
            #pragma unroll
            for (int sub = 0; sub < 4; ++sub) {
                bfrag b0 = *(bfrag*)&Ks[(sub * 16 + n) * P2 + quad * 8];
                bfrag b1 = *(bfrag*)&Ks[(sub * 16 + n) * P2 + 32 + quad * 8];
                ffrag c = {};
                c = MFMA(qa0, b0, c);
                c = MFMA(qa1, b1, c);
                const int k = kt * 64 + sub * 16 + n;
                float* prow = pbh + (size_t)(qt * 64 + qrow) * Sc + k;
                if (!bnd) {
                    #pragma unroll
                    for (int reg = 0; reg < 4; ++reg) {
                        float p = __expf((c[reg] + ts0[reg]) * SCALE) * rinv[reg];
                        prow[(size_t)reg * Sc] = p;
                        Pt[(qrow + reg) * P2 + sub * 16 + n] = (unsigned short)f2bf(p);
                    }
                } else {
                    #pragma unroll
                    for (int reg = 0; reg < 4; ++reg) {
                        int jrel = k - (qt * 64 + qrow + reg) + 32;
                        float p = 0.f;
                        if (jrel <= 32) {
                            int jcl = jrel < 0 ? 0 : jrel;
                            p = __expf((c[reg] + Ts[(qrow + reg) * 33 + jcl]) * SCALE) * rinv[reg];
                        }
                        prow[(size_t)reg * Sc] = p;
                        Pt[(qrow + reg) * P2 + sub * 16 + n] = (unsigned short)f2bf(p);
                        if ((unsigned)(jrel - 1) < 32u) Ws[(qrow + reg) * 32 + jrel - 1] = p;
                    }
                }
            }
            __syncthreads();   // Pt/Ws complete; scores done with Ks
            // PV: O^T += V^T . P^T
            bfrag pb0 = *(bfrag*)&Pt[(wv * 16 + n) * P2 + quad * 8];
            bfrag pb1 = *(bfrag*)&Pt[(wv * 16 + n) * P2 + 32 + quad * 8];
            #pragma unroll
            for (int ds = 0; ds < 4; ++ds) {
                bfrag va0 = *(bfrag*)&Vt[(ds * 16 + n) * P2 + quad * 8];
                bfrag va1 = *(bfrag*)&Vt[(ds * 16 + n) * P2 + 32 + quad * 8];
                oacc[ds] = MFMA(va0, pb0, oacc[ds]);
                oacc[ds] = MFMA(va1, pb1, oacc[ds]);
            }
        }

        // ================= epilogue: rel-v term + store O =================
        __syncthreads();   // Ws complete, PV done
        if (tid < 64) {
            float s = 0.f;
            #pragma unroll
            for (int j = 0; j < 32; ++j) s += Ws[tid * 32 + j];
            W0[tid] = 1.f - s;   // mass of far past (jrel<=0)
        }
        {   // Pt[q][jj] <- Ws (bf16), jj = jrel-1 in 0..31
            int q = tid >> 2, j0 = (tid & 3) * 8;
            #pragma unroll
            for (int i = 0; i < 8; i += 2) {
                unsigned pk = (unsigned)f2bf(Ws[q * 32 + j0 + i]) |
                              ((unsigned)f2bf(Ws[q * 32 + j0 + i + 1]) << 16);
                *(unsigned*)&Pt[q * P2 + j0 + i] = pk;
            }
        }
        {   // Vt[d][jj] <- pe_v[jj+1][d]
            int jj = tid >> 3, d0 = (tid & 7) * 8;
            const float* src = pev + (size_t)(jj + 1) * Dc + d0;
            float4 a = *(const float4*)(src);
            float4 b = *(const float4*)(src + 4);
            float vr[8] = {a.x, a.y, a.z, a.w, b.x, b.y, b.z, b.w};
            #pragma unroll
            for (int i = 0; i < 8; ++i)
                Vt[(d0 + i) * P2 + jj] = (unsigned short)f2bf(vr[i]);
        }
        __syncthreads();
        {
            bfrag pb = *(bfrag*)&Pt[(wv * 16 + n) * P2 + quad * 8];
            #pragma unroll
            for (int ds = 0; ds < 4; ++ds) {
                bfrag va = *(bfrag*)&Vt[(ds * 16 + n) * P2 + quad * 8];
                oacc[ds] = MFMA(va, pb, oacc[ds]);
            }
        }
        float w0q = W0[wv * 16 + n];
        __syncthreads();   // all LDS reads done before Ot overwrites Ks/Vt
        #pragma unroll
        for (int ds = 0; ds < 4; ++ds) {
            float4 ov;
            ov.x = oacc[ds][0] + w0q * pev[ds * 16 + quad * 4 + 0];
            ov.y = oacc[ds][1] + w0q * pev[ds * 16 + quad * 4 + 1];
            ov.z = oacc[ds][2] + w0q * pev[ds * 16 + quad * 4 + 2];
            ov.w = oacc[ds][3] + w0q * pev[ds * 16 + quad * 4 + 3];
            *(float4*)&Ot[(wv * 16 + n) * 68 + ds * 16 + quad * 4] = ov;
        }
        __syncthreads();
        {
            int r = tid >> 2, c0 = (tid & 3) * 16;
            float* dst = obh + (size_t)(qt * 64 + r) * Dc + c0;
            *(float4*)(dst)      = *(float4*)&Ot[r * 68 + c0];
            *(float4*)(dst + 4)  = *(float4*)&Ot[r * 68 + c0 + 4];
            *(float4*)(dst + 8)  = *(float4*)&Ot[r * 68 + c0 + 8];
            *(float4*)(dst + 12) = *(float4*)&Ot[r * 68 + c0 + 12];
        }
    }
}

extern "C" void kernel_launch(void* const* d_in, const int* in_sizes, int n_in,
                              void* d_out, int out_size, void* d_ws, size_t ws_size,
                              hipStream_t stream)
{
    const float* Q   = (const float*)d_in[0];
    const float* K   = (const float*)d_in[1];
    const float* V   = (const float*)d_in[2];
    const float* pek = (const float*)d_in[3];
    const float* pev = (const float*)d_in[4];
    float* out  = (float*)d_out;
    float* pbuf = out + (size_t)64 * Sc * Dc;   // p_attn follows output

    dim3 grid(8, 64);   // paired q-tiles (b, 15-b): uniform work per block
    relattn<<<grid, 256, 0, stream>>>(Q, K, V, pek, pev, out, pbuf);
}